// Round 4
// baseline (107.599 us; speedup 1.0000x reference)
//
#include <hip/hip_runtime.h>

#define NH 6
#define HEAD_DIM 32
#define CCH 192
#define HH 56
#define WW 56
#define HWSZ (HH * WW)            // 3136
#define KPOS 9
// 32^-0.5 * log2(e): fold softmax scale into exp2 domain
#define SCALE_LOG2E 0.25503486f
#define XPAD 61                   // dword stride per d-row (conflict-free: 2 lanes/bank)
#define ROWSZ (HEAD_DIM * XPAD)   // 1952 dwords per staged row-plane
#define JROWS 4                   // output rows per block (same parity)
#define STRIPS 7                  // strips per parity (7*4 = 28 rows)

// ---- fp16 pair packing: dword[x'] = (K[x'], K[x'+2]) so one ds_read2_b32
//      (dwords px, px+2) delivers all 3 dilated taps {px, px+2, px+4}.
//      R2 post-mortem: kernel is LDS-latency-chain bound (144 read->FMA
//      round-trips/iter, all pipes <30%); this cuts events 3x. ----
typedef __fp16 h2_t __attribute__((ext_vector_type(2)));   // matches cvt_pkrtz return type

__device__ __forceinline__ unsigned pack_pair(float a, float b) {
    h2_t h = __builtin_amdgcn_cvt_pkrtz(a, b);   // v_cvt_pkrtz_f16_f32, 1 VALU
    unsigned u;
    __builtin_memcpy(&u, &h, 4);
    return u;
}
__device__ __forceinline__ float lo_f(unsigned u) {
    unsigned short s = (unsigned short)(u & 0xffffu);
    __fp16 h;
    __builtin_memcpy(&h, &s, 2);
    return (float)h;        // v_cvt_f32_f16
}
__device__ __forceinline__ float hi_f(unsigned u) {
    unsigned short s = (unsigned short)(u >> 16);
    __fp16 h;
    __builtin_memcpy(&h, &s, 2);
    return (float)h;
}

// DPP quad_perm cross-lane adds: pure-VALU xor1/xor2 within 4-lane quads
// (c = lane&3, quad = pixel). Guard (px<56) is quad-uniform.
__device__ __forceinline__ float quad_xor1(float x) {
    return __int_as_float(
        __builtin_amdgcn_update_dpp(0, __float_as_int(x), 0xB1, 0xF, 0xF, true));
}
__device__ __forceinline__ float quad_xor2(float x) {
    return __int_as_float(
        __builtin_amdgcn_update_dpp(0, __float_as_int(x), 0x4E, 0xF, 0xF, true));
}

// Block = (bh, parity, strip). Outputs rows y0+2j, j=0..3. LDS = 3-slot ring
// of k/v row-planes as fp16 dup-pairs in [d][x'] dword layout (XPAD 61).
// Rolling schedule unchanged from R0: prefetch row r=j+3 (+next q) into regs
// DURING compute of row j, commit to slot j%3 after the barrier. 672 blocks
// x 46.8KB = 3 blocks/CU, whole grid co-resident.
__global__ __launch_bounds__(256, 4) void dilate_attn_h2(
    const float* __restrict__ q,
    const float* __restrict__ k,
    const float* __restrict__ v,
    float* __restrict__ out)
{
    __shared__ unsigned ks[3][ROWSZ];
    __shared__ unsigned vs[3][ROWSZ];

    const int bh     = blockIdx.x % 48;
    const int ps     = blockIdx.x / 48;
    const int parity = ps / STRIPS;
    const int s      = ps % STRIPS;
    const int y0     = parity + 8 * s;    // output rows y0 + 2j
    const int t      = threadIdx.x;

    const size_t plane = (size_t)bh * HEAD_DIM * HWSZ;
    const int px = t >> 2;                // 0..63 (valid < 56)
    const int c  = t & 3;                 // dim-octet
    const bool active = px < WW;

    // staging element map: 7 elems/thread per row (7*256 = 1792 = 32*56).
    // gofs = global offset (d*HWSZ + x); sa = LDS dword index (d*XPAD + x + 2).
    // edgemask: x<2 -> also write dword[x] = (0, K[x+2]=k[x]).
    // okmask: x+2 < 56 -> neighbor load valid (else 0 pad).
    int gofs[7], sa[7];
    unsigned edgemask = 0, okmask = 0;
#pragma unroll
    for (int i = 0; i < 7; i++) {
        const int e = t + 256 * i;
        const int d = e / WW;
        const int x = e - d * WW;
        gofs[i] = d * HWSZ + x;
        sa[i]   = d * XPAD + x + 2;
        if (x < 2)      edgemask |= 1u << i;
        if (x + 2 < WW) okmask   |= 1u << i;
    }

    // ---- q for row 0 (issue first; overlaps prologue staging) ----
    float qcur[8];
    if (active) {
        const float* qb = q + plane + (size_t)(8 * c) * HWSZ + (size_t)y0 * WW + px;
#pragma unroll
        for (int j = 0; j < 8; j++) qcur[j] = qb[j * HWSZ];
    }

    // ---- prologue: stage rows r=0,1,2 (ky = y0-2+2r) into slots 0,1,2 ----
#pragma unroll
    for (int r = 0; r < 3; r++) {
        const int ky   = y0 - 2 + 2 * r;
        const bool okr = (ky >= 0) && (ky < HH);
        const float* kb = k + plane + (size_t)(okr ? ky : 0) * WW;
        const float* vb = v + plane + (size_t)(okr ? ky : 0) * WW;
        float ka[7], kn[7], va[7], vn[7];
#pragma unroll
        for (int i = 0; i < 7; i++) {
            const bool ok2 = okr && ((okmask >> i) & 1);
            ka[i] = okr ? kb[gofs[i]]     : 0.0f;
            kn[i] = ok2 ? kb[gofs[i] + 2] : 0.0f;
            va[i] = okr ? vb[gofs[i]]     : 0.0f;
            vn[i] = ok2 ? vb[gofs[i] + 2] : 0.0f;
        }
#pragma unroll
        for (int i = 0; i < 7; i++) {
            ks[r][sa[i]] = pack_pair(ka[i], kn[i]);
            vs[r][sa[i]] = pack_pair(va[i], vn[i]);
            if ((edgemask >> i) & 1) {    // left pad dwords 0,1: (0, k[x])
                ks[r][sa[i] - 2] = pack_pair(0.0f, ka[i]);
                vs[r][sa[i] - 2] = pack_pair(0.0f, va[i]);
            }
        }
    }
    __syncthreads();

    // ---- main rolling loop over the 4 output rows ----
    float qnxt[8];
    float kaN[7], knN[7], vaN[7], vnN[7];   // raw f32 in flight across compute
#pragma unroll
    for (int j = 0; j < JROWS; j++) {
        const int y = y0 + 2 * j;

        // prefetch staged row r=j+3 (ky = y0+4+2j) + next q into registers
        if (j < 3) {
            const int ky   = y0 + 4 + 2 * j;       // always >= 4
            const bool okr = (ky < HH);
            const float* kb = k + plane + (size_t)(okr ? ky : 0) * WW;
            const float* vb = v + plane + (size_t)(okr ? ky : 0) * WW;
#pragma unroll
            for (int i = 0; i < 7; i++) {
                const bool ok2 = okr && ((okmask >> i) & 1);
                kaN[i] = okr ? kb[gofs[i]]     : 0.0f;
                knN[i] = ok2 ? kb[gofs[i] + 2] : 0.0f;
                vaN[i] = okr ? vb[gofs[i]]     : 0.0f;
                vnN[i] = ok2 ? vb[gofs[i] + 2] : 0.0f;
            }
            if (active) {
                const float* qb = q + plane + (size_t)(8 * c) * HWSZ + (size_t)(y + 2) * WW + px;
#pragma unroll
                for (int jj = 0; jj < 8; jj++) qnxt[jj] = qb[jj * HWSZ];
            }
        }

        // compute output row j from slots (j+r')%3, r'=0..2 (loads in flight)
        if (active) {
            float lg[KPOS];
#pragma unroll
            for (int rp = 0; rp < 3; rp++) {
                const unsigned* kr = &ks[(j + rp) % 3][(8 * c) * XPAD + px];
                unsigned r0[8], r1[8];
#pragma unroll
                for (int j8 = 0; j8 < 8; j8++) {     // batch-issue 8 ds_read2_b32
                    r0[j8] = kr[j8 * XPAD];
                    r1[j8] = kr[j8 * XPAD + 2];
                }
                float a0 = 0.f, a1 = 0.f, a2 = 0.f;
#pragma unroll
                for (int j8 = 0; j8 < 8; j8++) {
                    const float qj = qcur[j8];
                    a0 = fmaf(qj, lo_f(r0[j8]), a0);   // K[px]
                    a1 = fmaf(qj, hi_f(r0[j8]), a1);   // K[px+2]
                    a2 = fmaf(qj, hi_f(r1[j8]), a2);   // K[px+4]
                }
                lg[3 * rp + 0] = a0;
                lg[3 * rp + 1] = a1;
                lg[3 * rp + 2] = a2;
            }
            // quad reduction via DPP (VALU) — no LDS-pipe traffic
#pragma unroll
            for (int kk = 0; kk < KPOS; kk++) {
                float sm = lg[kk];
                sm += quad_xor1(sm);
                sm += quad_xor2(sm);
                lg[kk] = sm * SCALE_LOG2E;   // logits in log2 domain
            }
            const float m = fmaxf(fmaxf(fmaxf(lg[0], lg[1]), lg[2]),
                                  fmaxf(fmaxf(fmaxf(lg[3], lg[4]), lg[5]),
                                        fmaxf(fmaxf(lg[6], lg[7]), lg[8])));
            float ssum = 0.f;
#pragma unroll
            for (int kk = 0; kk < KPOS; kk++) {
                lg[kk] = exp2f(lg[kk] - m);
                ssum += lg[kk];
            }
            const float inv = __builtin_amdgcn_rcpf(ssum);

            // PV with unnormalized weights; normalize at epilogue.
            float acc[8];
#pragma unroll
            for (int jj = 0; jj < 8; jj++) acc[jj] = 0.f;
#pragma unroll
            for (int rp = 0; rp < 3; rp++) {
                const unsigned* vr = &vs[(j + rp) % 3][(8 * c) * XPAD + px];
                unsigned r0[8], r1[8];
#pragma unroll
                for (int j8 = 0; j8 < 8; j8++) {
                    r0[j8] = vr[j8 * XPAD];
                    r1[j8] = vr[j8 * XPAD + 2];
                }
                const float w0 = lg[3 * rp + 0];
                const float w1 = lg[3 * rp + 1];
                const float w2 = lg[3 * rp + 2];
#pragma unroll
                for (int j8 = 0; j8 < 8; j8++) {
                    float a = acc[j8];
                    a = fmaf(w0, lo_f(r0[j8]), a);
                    a = fmaf(w1, hi_f(r0[j8]), a);
                    a = fmaf(w2, hi_f(r1[j8]), a);
                    acc[j8] = a;
                }
            }

            const int h = bh % NH;
            const int b = bh / NH;
            float* ob = out + ((size_t)((b * HH + y) * WW + px)) * CCH
                            + h * HEAD_DIM + 8 * c;
            reinterpret_cast<float4*>(ob)[0] =
                make_float4(acc[0] * inv, acc[1] * inv, acc[2] * inv, acc[3] * inv);
            reinterpret_cast<float4*>(ob)[1] =
                make_float4(acc[4] * inv, acc[5] * inv, acc[6] * inv, acc[7] * inv);
        }

        __syncthreads();    // all waves done reading slot j%3

        if (j < 3) {
            // commit prefetched row r=j+3 into slot j%3 (pack now, not earlier,
            // so the vmcnt wait lands here instead of before compute); roll q
#pragma unroll
            for (int i = 0; i < 7; i++) {
                ks[j % 3][sa[i]] = pack_pair(kaN[i], knN[i]);
                vs[j % 3][sa[i]] = pack_pair(vaN[i], vnN[i]);
                if ((edgemask >> i) & 1) {
                    ks[j % 3][sa[i] - 2] = pack_pair(0.0f, kaN[i]);
                    vs[j % 3][sa[i] - 2] = pack_pair(0.0f, vaN[i]);
                }
            }
#pragma unroll
            for (int jj = 0; jj < 8; jj++) qcur[jj] = qnxt[jj];
        }

        __syncthreads();    // new slot contents visible before next compute
    }
}

extern "C" void kernel_launch(void* const* d_in, const int* in_sizes, int n_in,
                              void* d_out, int out_size, void* d_ws, size_t ws_size,
                              hipStream_t stream) {
    const float* q = (const float*)d_in[0];
    const float* k = (const float*)d_in[1];
    const float* v = (const float*)d_in[2];
    float* out = (float*)d_out;

    const int blocks = 48 * 2 * STRIPS;   // 672 — fully co-resident at 3/CU
    dilate_attn_h2<<<blocks, 256, 0, stream>>>(q, k, v, out);
}

// Round 5
// 104.849 us; speedup vs baseline: 1.0262x; 1.0262x over previous
//
#include <hip/hip_runtime.h>

#define NH 6
#define HEAD_DIM 32
#define CCH 192
#define HH 56
#define WW 56
#define HWSZ (HH * WW)            // 3136
#define KPOS 9
// 32^-0.5 * log2(e): fold softmax scale into exp2 domain
#define SCALE_LOG2E 0.25503486f
#define XPAD 61                   // x-stride: conflict-free reads & writes (R5-proven)
#define ROWSZ (HEAD_DIM * XPAD)   // 1952 floats per staged row-plane
#define JROWS 4                   // output rows per block (same parity)
#define STRIPS 7                  // strips per parity (7*4 = 28 rows)

// DPP quad_perm cross-lane adds: pure-VALU replacement for __shfl_xor(x,1/2),
// which lowers to ds_bpermute (LDS pipe). Reduction is within quads of 4 lanes
// (c = lane&3, quad = pixel); quad_perm [1,0,3,2] = xor1, [2,3,0,1] = xor2.
// Guard (px<56) is quad-uniform, so DPP source lanes are always active inside
// the guarded region.
__device__ __forceinline__ float quad_xor1(float x) {
    return __int_as_float(
        __builtin_amdgcn_update_dpp(0, __float_as_int(x), 0xB1, 0xF, 0xF, true));
}
__device__ __forceinline__ float quad_xor2(float x) {
    return __int_as_float(
        __builtin_amdgcn_update_dpp(0, __float_as_int(x), 0x4E, 0xF, 0xF, true));
}

// Block = (bh, parity, strip). Outputs rows y0+2j, j=0..3. LDS = 3-slot ring
// of k/v row-planes in [d][x'] layout (XPAD 61, zero-pad baked in). Rolling
// schedule: prefetch row r=j+3 (and next q) into regs DURING compute of row j,
// commit to slot j%3 after the barrier. 672 blocks x 46.8KB = whole grid
// co-resident at 3 blocks/CU; every compute phase has loads in flight.
//
// Session conclusion (R0-R4): dur_us = ~82us mandatory re-poison fills
// (2 x 268MB @ 6.5TB/s, visible as fillBufferAligned @ 80% HBM in every
// profile) + ~5us small restores + ~18-23us kernel, where the kernel's own
// traffic floor is ~12-16us. Three structural levers (2x occupancy, softmax
// shuffle->DPP, 3x fewer LDS events via fp16 pairs) all moved dur_us < noise
// except where they added work. This variant is the best-measured (104.8us,
// absmax 0.0078) — restored as the final kernel.
__global__ __launch_bounds__(256, 4) void dilate_attn_roll(
    const float* __restrict__ q,
    const float* __restrict__ k,
    const float* __restrict__ v,
    float* __restrict__ out)
{
    __shared__ float ks[3][ROWSZ];
    __shared__ float vs[3][ROWSZ];

    // bh fastest -> (bh, strip±1) partners 48 apart (same XCD, co-resident)
    const int bh     = blockIdx.x % 48;
    const int ps     = blockIdx.x / 48;
    const int parity = ps / STRIPS;
    const int s      = ps % STRIPS;
    const int y0     = parity + 8 * s;    // output rows y0 + 2j
    const int t      = threadIdx.x;

    const size_t plane = (size_t)bh * HEAD_DIM * HWSZ;
    const int px = t >> 2;                // 0..63 (valid < 56)
    const int c  = t & 3;                 // dim-octet
    const bool active = px < WW;

    // staging element map: 7 elems/thread per row (7*256 = 1792 = 32*56)
    int sd[7], sx[7];
#pragma unroll
    for (int i = 0; i < 7; i++) {
        const int e = t + 256 * i;
        sd[i] = e / WW;
        sx[i] = e - sd[i] * WW;
    }

    // ---- q for row 0 (issue first; overlaps prologue staging) ----
    float qcur[8];
    if (active) {
        const float* qb = q + plane + (size_t)(8 * c) * HWSZ + (size_t)y0 * WW + px;
#pragma unroll
        for (int j = 0; j < 8; j++) qcur[j] = qb[j * HWSZ];
    }

    // ---- zero pad columns x' in {0,1,58,59} for all 3 slots (done ONCE;
    //      row data never overwrites pads) ----
    for (int e = t; e < 3 * HEAD_DIM * 4; e += 256) {
        const int slot = e >> 7;
        const int rr   = e & 127;
        const int d    = rr >> 2;
        const int xc   = rr & 3;
        const int xp   = (xc < 2) ? xc : (56 + xc);
        ks[slot][d * XPAD + xp] = 0.0f;
        vs[slot][d * XPAD + xp] = 0.0f;
    }

    // ---- prologue: stage rows r=0,1,2 (ky = y0-2+2r) into slots 0,1,2 ----
    float kpre[7], vpre[7];
#pragma unroll
    for (int r = 0; r < 3; r++) {
        const int ky   = y0 - 2 + 2 * r;
        const bool okr = (ky >= 0) && (ky < HH);
#pragma unroll
        for (int i = 0; i < 7; i++) {
            const size_t g = plane + (size_t)sd[i] * HWSZ + (size_t)(okr ? ky : 0) * WW + sx[i];
            kpre[i] = okr ? k[g] : 0.0f;
            vpre[i] = okr ? v[g] : 0.0f;
        }
#pragma unroll
        for (int i = 0; i < 7; i++) {
            const int a = sd[i] * XPAD + sx[i] + 2;
            ks[r][a] = kpre[i];
            vs[r][a] = vpre[i];
        }
    }
    __syncthreads();

    // ---- main rolling loop over the 4 output rows ----
    float qnxt[8];
#pragma unroll
    for (int j = 0; j < JROWS; j++) {
        const int y = y0 + 2 * j;

        // prefetch staged row r=j+3 (ky = y0+4+2j) + next q into registers
        if (j < 3) {
            const int ky   = y0 + 4 + 2 * j;       // always >= 4
            const bool okr = (ky < HH);
#pragma unroll
            for (int i = 0; i < 7; i++) {
                const size_t g = plane + (size_t)sd[i] * HWSZ + (size_t)(okr ? ky : 0) * WW + sx[i];
                kpre[i] = okr ? k[g] : 0.0f;
                vpre[i] = okr ? v[g] : 0.0f;
            }
            if (active) {
                const float* qb = q + plane + (size_t)(8 * c) * HWSZ + (size_t)(y + 2) * WW + px;
#pragma unroll
                for (int jj = 0; jj < 8; jj++) qnxt[jj] = qb[jj * HWSZ];
            }
        }

        // compute output row j from slots (j+r')%3, r'=0..2 (loads in flight)
        if (active) {
            float lg[KPOS];
#pragma unroll
            for (int rp = 0; rp < 3; rp++) {
                const float* kr = &ks[(j + rp) % 3][(8 * c) * XPAD + px];
                float a0 = 0.f, a1 = 0.f, a2 = 0.f;
#pragma unroll
                for (int j8 = 0; j8 < 8; j8++) {
                    const float* p  = kr + j8 * XPAD;
                    const float qj = qcur[j8];
                    a0 = fmaf(qj, p[0], a0);
                    a1 = fmaf(qj, p[2], a1);
                    a2 = fmaf(qj, p[4], a2);
                }
                lg[3 * rp + 0] = a0;
                lg[3 * rp + 1] = a1;
                lg[3 * rp + 2] = a2;
            }
            // quad reduction via DPP (VALU) — no LDS-pipe traffic
#pragma unroll
            for (int kk = 0; kk < KPOS; kk++) {
                float sm = lg[kk];
                sm += quad_xor1(sm);
                sm += quad_xor2(sm);
                lg[kk] = sm * SCALE_LOG2E;   // logits in log2 domain
            }
            // tree max (depth 2; clang fuses v_max3)
            const float m = fmaxf(fmaxf(fmaxf(lg[0], lg[1]), lg[2]),
                                  fmaxf(fmaxf(fmaxf(lg[3], lg[4]), lg[5]),
                                        fmaxf(fmaxf(lg[6], lg[7]), lg[8])));
            float ssum = 0.f;
#pragma unroll
            for (int kk = 0; kk < KPOS; kk++) {
                lg[kk] = exp2f(lg[kk] - m);   // single v_exp_f32
                ssum += lg[kk];
            }
            const float inv = __builtin_amdgcn_rcpf(ssum);

            // PV with UNNORMALIZED weights (bounded <=1); normalize at epilogue.
            // rcp latency hides under the PV FMAs.
            float acc[8];
#pragma unroll
            for (int jj = 0; jj < 8; jj++) acc[jj] = 0.f;
#pragma unroll
            for (int rp = 0; rp < 3; rp++) {
                const float* vr = &vs[(j + rp) % 3][(8 * c) * XPAD + px];
                const float w0 = lg[3 * rp + 0];
                const float w1 = lg[3 * rp + 1];
                const float w2 = lg[3 * rp + 2];
#pragma unroll
                for (int jj = 0; jj < 8; jj++) {
                    const float* p = vr + jj * XPAD;
                    float a = acc[jj];
                    a = fmaf(w0, p[0], a);
                    a = fmaf(w1, p[2], a);
                    a = fmaf(w2, p[4], a);
                    acc[jj] = a;
                }
            }

            const int h = bh % NH;
            const int b = bh / NH;
            float* ob = out + ((size_t)((b * HH + y) * WW + px)) * CCH
                            + h * HEAD_DIM + 8 * c;
            reinterpret_cast<float4*>(ob)[0] =
                make_float4(acc[0] * inv, acc[1] * inv, acc[2] * inv, acc[3] * inv);
            reinterpret_cast<float4*>(ob)[1] =
                make_float4(acc[4] * inv, acc[5] * inv, acc[6] * inv, acc[7] * inv);
        }

        __syncthreads();    // all waves done reading slot j%3

        if (j < 3) {
            // commit prefetched row r=j+3 into slot j%3; roll q
#pragma unroll
            for (int i = 0; i < 7; i++) {
                const int a = sd[i] * XPAD + sx[i] + 2;
                ks[j % 3][a] = kpre[i];
                vs[j % 3][a] = vpre[i];
            }
#pragma unroll
            for (int jj = 0; jj < 8; jj++) qcur[jj] = qnxt[jj];
        }

        __syncthreads();    // new slot contents visible before next compute
    }
}

extern "C" void kernel_launch(void* const* d_in, const int* in_sizes, int n_in,
                              void* d_out, int out_size, void* d_ws, size_t ws_size,
                              hipStream_t stream) {
    const float* q = (const float*)d_in[0];
    const float* k = (const float*)d_in[1];
    const float* v = (const float*)d_in[2];
    float* out = (float*)d_out;

    const int blocks = 48 * 2 * STRIPS;   // 672 — fully co-resident at 3/CU
    dilate_attn_roll<<<blocks, 256, 0, stream>>>(q, k, v, out);
}